// Round 1
// baseline (156.427 us; speedup 1.0000x reference)
//
#include <hip/hip_runtime.h>
#include <hip/hip_fp16.h>

#define HH 512
#define WW 512
#define NCH 3
#define NBATCH 16
#define NIMG (NBATCH*NCH)     // 48
#define CHUNK 32              // output rows per wave
#define NCHUNK (HH/CHUNK)     // 16
#define NSTRIP 4              // 128-col strips
#define SW 128
#define NT 64                 // one wave per block -> no barriers anywhere
#define NROWS (CHUNK+10)      // 42 input rows per wave
#define BLKS_PER_B (NCH*NCHUNK*NSTRIP)   // 192 partial slots per batch elem
#define NPAIR 70              // pair slots: cols c0-6 .. c0+133, 2 cols/slot

struct RowData { float4 m; float4 h; };
union RingQ { float4 f; __half2 h[4]; };

// R8: row staging is pair-major float4 (slot k = cols c0-6+2k, c0-5+2k as
// x0,y0,x1,y1). Write = ONE b128 at 16B/lane stride (conflict-free), taps =
// 7 b128 at 16B/lane stride (conflict-free). The old layout's two b64 writes
// at 16B lane stride were 8-way bank conflicts = 5.09M cycles/dispatch (~14%
// of CU time). Tap vectors are reassembled as (v[j].zw, v[j+1].xy) so the
// summation sequence is bit-identical to R7 (absmax stays 0.0).
__global__ __launch_bounds__(NT) void ssim_main(
    const float* __restrict__ pred, const float* __restrict__ targ,
    float* __restrict__ ws)
{
  // all 70 slots rewritten every iteration (halo lanes write zeros when the
  // pair is outside the image) -> no init, no stale reads; same-wave LDS is
  // in-order so no barriers (validated R2-R7, absmax 0.0)
  __shared__ __align__(16) float4 rowp[NPAIR];
  // fp16 ring of horizontal sums: one 16B word per (slot,lane):
  // {c0:(hx,hy),(hxy,hss), c1:(hx,hy),(hxy,hss)} — read/write as b128
  __shared__ __align__(16) float4 ring[11][NT];

  const int l = threadIdx.x;
  const int blk = blockIdx.x;
  const int img = blk >> 6;              // / (NCHUNK*NSTRIP)
  const int rem = blk & 63;
  const int chunk = rem >> 2;
  const int strip = rem & 3;

  const int r0 = chunk*CHUNK - 5;        // first input row
  const int c0 = strip*SW;

  const size_t ib = (size_t)img * (size_t)(HH*WW);
  const float* pp = pred + ib;
  const float* tp = targ + ib;

  const int cm = c0 + 2*l;               // this lane's 2 main cols

  // halo duty: lanes 58..63 own pair slots {0,1,2, 67,68,69}
  const int hj = l - 58;                 // 0..5 on halo lanes, else negative
  const bool isH = (hj >= 0);
  const int hslot = (hj < 3) ? hj : (64 + hj);          // 0..2 / 67..69
  const int hcol  = (hj < 3) ? (c0 - 6 + 2*hj)          // left pair first col
                             : (c0 + 122 + 2*hj);       // right pair first col
  const bool hvalid = isH && ((hj < 3) ? (c0 > 0) : (c0 < 384));

  auto loadrow = [&](int it) -> RowData {
    RowData d;
    const int r = r0 + it;
    if ((unsigned)r < (unsigned)HH) {    // wave-uniform branch
      const size_t ro = (size_t)r * WW;
      const float2 x = *(const float2*)(pp + ro + cm);
      const float2 y = *(const float2*)(tp + ro + cm);
      d.m = make_float4(x.x, x.y, y.x, y.y);
      if (hvalid) {
        const float2 hx = *(const float2*)(pp + ro + hcol);
        const float2 hy = *(const float2*)(tp + ro + hcol);
        d.h = make_float4(hx.x, hx.y, hy.x, hy.y);
      } else {
        d.h = make_float4(0.f, 0.f, 0.f, 0.f);
      }
    } else {
      d.m = make_float4(0.f, 0.f, 0.f, 0.f);
      d.h = make_float4(0.f, 0.f, 0.f, 0.f);
    }
    return d;
  };

  // vertical running sums: (x, y, xy, ss=xx+yy) per col — registers
  float2 vx = make_float2(0.f,0.f), vy = vx, vxy = vx, vss = vx;
  float acc = 0.f;

  // 3-deep global prefetch
  RowData cur = loadrow(0);
  RowData nxt = loadrow(1);
  RowData nx2 = loadrow(2);

  constexpr float c1 = 0.0001f, c2 = 0.0009f, inv121 = 1.0f/121.0f;

  auto ssim1 = [&](float Sx, float Sy, float Sxy, float Sss) -> float {
    const float mux = Sx*inv121, muy = Sy*inv121;
    const float muxy = mux*muy;
    const float m2   = fmaf(mux, mux, muy*muy);
    const float sgxy = fmaf(Sxy, inv121, -muxy);
    const float sgss = fmaf(Sss, inv121, -m2);
    const float num = fmaf(2.f, muxy, c1) * fmaf(2.f, sgxy, c2);
    const float den = (m2 + c1) * (sgss + c2);
    const float s = num * __builtin_amdgcn_rcpf(den);
    return fminf(fmaxf(s, 0.f), 1.f);
  };

  auto body = [&](int it, int slot, bool dosub, bool doemit) {
    // ring-old read hoisted first: independent of this row's staging, so its
    // latency overlaps the staging write + tap reads
    RingQ ou;
    if (dosub) ou.f = ring[slot][l];

    // stage row it: one conflict-free b128 per lane (pair-major layout)
    rowp[3 + l] = make_float4(cur.m.x, cur.m.z, cur.m.y, cur.m.w);
    if (isH) rowp[hslot] = make_float4(cur.h.x, cur.h.z, cur.h.y, cur.h.w);
    cur = nxt; nxt = nx2;
    nx2 = loadrow(it + 3);               // global prefetch 3 rows ahead

    // pair slots l..l+6 cover cols 2l-6 .. 2l+7; taps p0..p11 = cols 2l-5..2l+6
    const float4* tb = rowp + l;
    float4 v[7];
    #pragma unroll
    for (int j = 0; j < 7; ++j) v[j] = tb[j];

    float sx=0.f, sy=0.f, sxy=0.f, sss=0.f;
    float x0=0.f, y0=0.f, x11=0.f, y11=0.f;
    #pragma unroll
    for (int j = 0; j < 6; ++j) {
      // identical arithmetic sequence to R7: tv = (x[p],y[p],x[p+1],y[p+1]), p=2j
      const float4 tv = make_float4(v[j].z, v[j].w, v[j+1].x, v[j+1].y);
      if (j == 0) { x0 = tv.x; y0 = tv.y; }
      sx += tv.x; sy += tv.y;
      sxy = fmaf(tv.x, tv.y, sxy);
      sss = fmaf(tv.x, tv.x, sss);
      sss = fmaf(tv.y, tv.y, sss);
      if (j < 5) {
        sx += tv.z; sy += tv.w;
        sxy = fmaf(tv.z, tv.w, sxy);
        sss = fmaf(tv.z, tv.z, sss);
        sss = fmaf(tv.w, tv.w, sss);
      } else { x11 = tv.z; y11 = tv.w; }
    }

    // col0 window = p0..p10 ; col1 = col0 - p0 + p11
    const float2 hx  = make_float2(sx,  sx - x0 + x11);
    const float2 hy  = make_float2(sy,  sy - y0 + y11);
    const float2 hxy = make_float2(sxy, fmaf(x11, y11, fmaf(-x0, y0, sxy)));
    const float2 hss = make_float2(sss,
        fmaf(x11, x11, fmaf(y11, y11, fmaf(-x0, x0, fmaf(-y0, y0, sss)))));

    // round h to fp16 once; add the rounded value and store the identical
    // rounded value -> later subtract cancels exactly (no drift)
    RingQ qu;
    qu.h[0] = __floats2half2_rn(hx.x,  hy.x);
    qu.h[1] = __floats2half2_rn(hxy.x, hss.x);
    qu.h[2] = __floats2half2_rn(hx.y,  hy.y);
    qu.h[3] = __floats2half2_rn(hxy.y, hss.y);
    ring[slot][l] = qu.f;                // ONE b128 write (conflict-free)
    const float2 a0 = __half22float2(qu.h[0]), a1 = __half22float2(qu.h[1]);
    const float2 a2 = __half22float2(qu.h[2]), a3 = __half22float2(qu.h[3]);

    if (dosub) {
      const float2 oxy0 = __half22float2(ou.h[0]), ops0 = __half22float2(ou.h[1]);
      const float2 oxy1 = __half22float2(ou.h[2]), ops1 = __half22float2(ou.h[3]);
      vx.x  -= oxy0.x; vy.x  -= oxy0.y; vxy.x -= ops0.x; vss.x -= ops0.y;
      vx.y  -= oxy1.x; vy.y  -= oxy1.y; vxy.y -= ops1.x; vss.y -= ops1.y;
    }
    vx.x += a0.x; vy.x += a0.y; vxy.x += a1.x; vss.x += a1.y;
    vx.y += a2.x; vy.y += a2.y; vxy.y += a3.x; vss.y += a3.y;

    if (doemit) {
      acc += ssim1(vx.x, vy.x, vxy.x, vss.x);
      acc += ssim1(vx.y, vy.y, vxy.y, vss.y);
    }
  };

  // 42 input rows: warmup 11 (first emit at it=10), steady 2x11, tail 9
  #pragma unroll
  for (int u = 0; u < 11; ++u) body(u, u, false, u == 10);
  for (int g = 0; g < 2; ++g) {
    #pragma unroll
    for (int u = 0; u < 11; ++u) body(11 + 11*g + u, u, true, true);
  }
  #pragma unroll
  for (int u = 0; u < 9; ++u) body(33 + u, u, true, true);

  // wave reduction -> per-block partial slot (written unconditionally: no
  // memset of d_ws needed, no atomics)
  #pragma unroll
  for (int off = 32; off > 0; off >>= 1) acc += __shfl_down(acc, off, 64);
  if (l == 0) ws[blk] = acc;
}

__global__ void ssim_final(const float* __restrict__ ws, float* __restrict__ out) {
  const int b = blockIdx.x;              // batch element
  const int t = threadIdx.x;             // 64 threads
  const float* p = ws + b * BLKS_PER_B;
  float s = p[t] + p[t + 64] + p[t + 128];
  #pragma unroll
  for (int off = 32; off > 0; off >>= 1) s += __shfl_down(s, off, 64);
  if (t == 0) out[b] = 1.0f - s * (1.0f / (float)(NCH*HH*WW));
}

extern "C" void kernel_launch(void* const* d_in, const int* in_sizes, int n_in,
                              void* d_out, int out_size, void* d_ws, size_t ws_size,
                              hipStream_t stream) {
  const float* pred = (const float*)d_in[0];
  const float* targ = (const float*)d_in[1];
  float* out = (float*)d_out;
  float* ws  = (float*)d_ws;
  ssim_main<<<dim3(NIMG*NCHUNK*NSTRIP), dim3(NT), 0, stream>>>(pred, targ, ws);
  ssim_final<<<dim3(NBATCH), dim3(64), 0, stream>>>(ws, out);
}